// Round 10
// baseline (240.826 us; speedup 1.0000x reference)
//
#include <hip/hip_runtime.h>
#include <hip/hip_bf16.h>
#include <math.h>

#define SDIM 4096
#define EMB 512
#define NH 8
#define HD 64
#define QBLK 128            // q-rows per block (4 waves x 32)
#define KVB 64
#define NB 2
#define NQT (SDIM / QBLK)   // 32
#define NPAIR (NQT / 2)     // 16

typedef __attribute__((ext_vector_type(4)))  float f32x4;
typedef __attribute__((ext_vector_type(16))) float f32x16;
typedef __attribute__((ext_vector_type(8)))  short bf16x8;
typedef __attribute__((ext_vector_type(4)))  unsigned u32x4;

#define SCQ 0.18033688011112042f   // log2(e) / sqrt(64), folded into Q
#define THR 8.0f                   // defer-max threshold, log2 units

__device__ __forceinline__ unsigned cvt_pk(float lo, float hi) {
    unsigned r;
    asm("v_cvt_pk_bf16_f32 %0, %1, %2" : "=v"(r) : "v"(lo), "v"(hi));
    return r;
}
__device__ __forceinline__ void pl32swap(unsigned &a, unsigned &b) {
    asm("v_permlane32_swap_b32 %0, %1" : "+v"(a), "+v"(b));
}

// ---------------------------------------------------------------------------
// Flash attention (causal). 512 blocks x 512 threads, 2 blocks/CU co-resident
// (LDS 66KB x2 = 132 <= 160KB; 16 waves x ~100 VGPR fits pool) -> 4 waves/SIMD.
// PLACEMENT MODEL (R7 evidence): CU fill is CONSECUTIVE (CU j <- blocks
// 2j,2j+1), NOT strided j,j+256 (R7 ran at heavy-serial speed with the
// strided layout). So interleave: block 2k = heavy q-tile (31-p), block
// 2k+1 = light (p), same bh -> each CU gets 33 team-iters, shared KV in L2.
// REGISTER MODEL (R4-R9): >=768-thread blocks pin VGPR low & spill
// (uncontrollable); 512-thread blocks allocate honestly (R7: 96, no spill).
// (512,4) caps at 128 for the 16-wave/CU target.
// Per block: 2 teams x 4 waves split KV tiles even/odd, private (m,l,O) +
// private double-buffered LDS; 2-way flash-combine. 32x32x16 MFMA, swapped
// QK^T (q lane-local), T12 repack, T13 defer-max, T14 async-STAGE, T2
// XOR-swizzle, T5 setprio.
// ---------------------------------------------------------------------------
__global__ __launch_bounds__(512, 4) void attn_fwd(
    const float* __restrict__ Q, const float* __restrict__ K,
    const float* __restrict__ V, short* __restrict__ X)
{
    __shared__ __align__(16) short smem[32768];   // 64KB: [team][buf][K|V]
    __shared__ float mlb[4][32][2];               // merge: per wave m,l

    int idx  = blockIdx.x;
    int k_   = idx >> 1;                // pair index 0..255
    int s_   = idx & 1;                 // 0 = heavy, 1 = light
    int bh   = k_ & 15;                 // pair shares bh -> shared KV in L2
    int p    = k_ >> 4;
    int qt   = s_ ? p : (NQT - 1 - p);
    int b = bh / NH, h = bh % NH;

    int tid  = threadIdx.x;
    int wave = tid >> 6, lane = tid & 63;
    int team = wave >> 2, w = wave & 3;
    int ln = lane & 31, hi = lane >> 5;
    int swz = 8 * (ln & 7);
    int shbase = 36 * hi;               // (lane&32) + 4*hi

    // per-team staging maps (256 threads per team)
    int ttid = tid & 255;
    const int kr = ttid >> 2, kc = (ttid & 3) * 16;   // K: row kr, 16 d
    const int vp = ttid & 31, vdb = (ttid >> 5) * 8;  // V: kv pair 2vp, 8 d

    // prefetch registers (T14)
    f32x4 pk0, pk1, pk2, pk3, pv0, pv1, pv2, pv3;

    auto ISSUE = [&](int k0) {
        const float* kp = K + ((size_t)(b * SDIM + k0 + kr)) * EMB + h * HD + kc;
        pk0 = *(const f32x4*)(kp + 0);
        pk1 = *(const f32x4*)(kp + 4);
        pk2 = *(const f32x4*)(kp + 8);
        pk3 = *(const f32x4*)(kp + 12);
        const float* v0p = V + ((size_t)(b * SDIM + k0 + 2 * vp)) * EMB + h * HD + vdb;
        pv0 = *(const f32x4*)(v0p);
        pv1 = *(const f32x4*)(v0p + 4);
        pv2 = *(const f32x4*)(v0p + EMB);
        pv3 = *(const f32x4*)(v0p + EMB + 4);
    };

    auto WRITE_STAGE = [&](int buf) {
        short* Klp = &smem[(team * 2 + buf) * 8192];
        short* Vtp = Klp + 4096;
        int rs = 8 * (kr & 7);
        u32x4 w0 = { cvt_pk(pk0[0],pk0[1]), cvt_pk(pk0[2],pk0[3]),
                     cvt_pk(pk1[0],pk1[1]), cvt_pk(pk1[2],pk1[3]) };
        u32x4 w1 = { cvt_pk(pk2[0],pk2[1]), cvt_pk(pk2[2],pk2[3]),
                     cvt_pk(pk3[0],pk3[1]), cvt_pk(pk3[2],pk3[3]) };
        *(u32x4*)&Klp[kr * HD + ((kc + 0) ^ rs)] = w0;
        *(u32x4*)&Klp[kr * HD + ((kc + 8) ^ rs)] = w1;
        unsigned* vt32 = (unsigned*)Vtp;
#pragma unroll
        for (int i = 0; i < 4; ++i) {
            int d = vdb + i;
            vt32[d * 32 + (vp ^ (4 * (d & 7)))] = cvt_pk(pv0[i], pv2[i]);
        }
#pragma unroll
        for (int i = 0; i < 4; ++i) {
            int d = vdb + 4 + i;
            vt32[d * 32 + (vp ^ (4 * (d & 7)))] = cvt_pk(pv1[i], pv3[i]);
        }
    };

    // per-segment state
    bf16x8 qf0, qf1, qf2, qf3;
    float m2, l_run;
    f32x16 accO0, accO1;
    int qbase, q_g;

    auto LOAD_Q = [&]() {   // pre-scaled by SCQ (log2-domain scores from MFMA)
        const float* qp = Q + ((size_t)(b * SDIM + q_g)) * EMB + h * HD + 8 * hi;
#pragma unroll
        for (int s = 0; s < 4; ++s) {
            f32x4 a = *(const f32x4*)(qp + 16 * s) * SCQ;
            f32x4 c = *(const f32x4*)(qp + 16 * s + 4) * SCQ;
            u32x4 wq = { cvt_pk(a[0], a[1]), cvt_pk(a[2], a[3]),
                         cvt_pk(c[0], c[1]), cvt_pk(c[2], c[3]) };
            bf16x8 f = (bf16x8)wq;
            if (s == 0) qf0 = f; else if (s == 1) qf1 = f;
            else if (s == 2) qf2 = f; else qf3 = f;
        }
    };

    auto COMPUTE = [&](int buf, int k0) {
        short* Klp = &smem[(team * 2 + buf) * 8192];
        short* Vtp = Klp + 4096;
        float p0[16], p1[16];
#pragma unroll
        for (int t = 0; t < 2; ++t) {
            f32x16 acc = (f32x16){0.f,0.f,0.f,0.f,0.f,0.f,0.f,0.f,
                                  0.f,0.f,0.f,0.f,0.f,0.f,0.f,0.f};
            __builtin_amdgcn_s_setprio(1);
#pragma unroll
            for (int s = 0; s < 4; ++s) {
                bf16x8 kf = *(bf16x8*)&Klp[(32*t + ln) * HD + ((16*s + 8*hi) ^ swz)];
                bf16x8 qs = (s == 0) ? qf0 : (s == 1) ? qf1 : (s == 2) ? qf2 : qf3;
                acc = __builtin_amdgcn_mfma_f32_32x32x16_bf16(kf, qs, acc, 0, 0, 0);
            }
            __builtin_amdgcn_s_setprio(0);
            float* pt = t ? p1 : p0;
            if (k0 + 32*t + 31 > qbase) {          // diagonal-crossing: mask
#pragma unroll
                for (int r = 0; r < 16; ++r) {
                    int kv = k0 + 32*t + (r & 3) + 8*(r >> 2) + 4*hi;
                    pt[r] = (kv > q_g) ? -INFINITY : acc[r];
                }
            } else {
#pragma unroll
                for (int r = 0; r < 16; ++r) pt[r] = acc[r];
            }
        }

        // tree max
        float mx[16];
#pragma unroll
        for (int r = 0; r < 16; ++r) mx[r] = fmaxf(p0[r], p1[r]);
#pragma unroll
        for (int r = 0; r < 8; ++r) mx[r] = fmaxf(mx[r], mx[r + 8]);
#pragma unroll
        for (int r = 0; r < 4; ++r) mx[r] = fmaxf(mx[r], mx[r + 4]);
        float mt = fmaxf(fmaxf(mx[0], mx[1]), fmaxf(mx[2], mx[3]));
        mt = fmaxf(mt, __shfl_xor(mt, 32, 64));

        if (!__all(mt <= m2 + THR)) {              // T13 defer-max
            float m_new = fmaxf(m2, mt);
            float fac = __builtin_amdgcn_exp2f(m2 - m_new);
            m2 = m_new;
            l_run *= fac;
#pragma unroll
            for (int r = 0; r < 16; ++r) {
                float fr = __shfl(fac, shbase + ((r & 3) + 8*(r >> 2)), 64);
                accO0[r] *= fr;
                accO1[r] *= fr;
            }
        }
        // exp2 + tree sum
        float sm[16];
#pragma unroll
        for (int r = 0; r < 16; ++r) {
            p0[r] = __builtin_amdgcn_exp2f(p0[r] - m2);
            p1[r] = __builtin_amdgcn_exp2f(p1[r] - m2);
            sm[r] = p0[r] + p1[r];
        }
#pragma unroll
        for (int r = 0; r < 8; ++r) sm[r] += sm[r + 8];
#pragma unroll
        for (int r = 0; r < 4; ++r) sm[r] += sm[r + 4];
        float psum = (sm[0] + sm[1]) + (sm[2] + sm[3]);
        psum += __shfl_xor(psum, 32, 64);
        l_run += psum;

        // T12 repack P -> A-frags + PV
#pragma unroll
        for (int s = 0; s < 4; ++s) {
            const float* pt = (s >= 2) ? p1 : p0;
            const int u8 = (s & 1) * 8;
            unsigned w0 = cvt_pk(pt[u8 + 0], pt[u8 + 1]);
            unsigned w2 = cvt_pk(pt[u8 + 4], pt[u8 + 5]);
            pl32swap(w0, w2);
            unsigned w1 = cvt_pk(pt[u8 + 2], pt[u8 + 3]);
            unsigned w3 = cvt_pk(pt[u8 + 6], pt[u8 + 7]);
            pl32swap(w1, w3);
            u32x4 pw = { w0, w1, w2, w3 };
            bf16x8 pa = (bf16x8)pw;
            bf16x8 v0f = *(bf16x8*)&Vtp[(ln)      * KVB + ((16*s + 8*hi) ^ swz)];
            bf16x8 v1f = *(bf16x8*)&Vtp[(32 + ln) * KVB + ((16*s + 8*hi) ^ swz)];
            __builtin_amdgcn_s_setprio(1);
            accO0 = __builtin_amdgcn_mfma_f32_32x32x16_bf16(pa, v0f, accO0, 0, 0, 0);
            accO1 = __builtin_amdgcn_mfma_f32_32x32x16_bf16(pa, v1f, accO1, 0, 0, 0);
            __builtin_amdgcn_s_setprio(0);
        }
    };

    // flash-combine merge (team1 -> LDS, team0 merges + writes X)
    auto FINISH = [&]() {
        __syncthreads();
        f32x4* O4 = (f32x4*)&smem[16384];   // 32KB overlay on team1 KV region
        if (team == 1) {
            if (hi == 0) { mlb[w][ln][0] = m2; mlb[w][ln][1] = l_run; }
#pragma unroll
            for (int rq = 0; rq < 4; ++rq)
                O4[(w * 8 + rq) * 64 + lane] =
                    (f32x4){accO0[4*rq], accO0[4*rq+1], accO0[4*rq+2], accO0[4*rq+3]};
#pragma unroll
            for (int rq = 0; rq < 4; ++rq)
                O4[(w * 8 + 4 + rq) * 64 + lane] =
                    (f32x4){accO1[4*rq], accO1[4*rq+1], accO1[4*rq+2], accO1[4*rq+3]};
        }
        __syncthreads();
        if (team == 0) {
            float mB = mlb[w][ln][0], lB = mlb[w][ln][1];
            float m  = fmaxf(m2, mB);
            float aS = __builtin_amdgcn_exp2f(m2 - m);
            float bS = __builtin_amdgcn_exp2f(mB - m);
            float il = 1.f / (l_run * aS + lB * bS);
            float fa = aS * il, fb = bS * il;
            f32x4 ob[8];
#pragma unroll
            for (int rq = 0; rq < 8; ++rq) ob[rq] = O4[(w * 8 + rq) * 64 + lane];
#pragma unroll
            for (int r = 0; r < 16; ++r) {
                int crow = (r & 3) + 8 * (r >> 2);
                float faR = __shfl(fa, shbase + crow, 64);
                float fbR = __shfl(fb, shbase + crow, 64);
                float o0 = accO0[r] * faR + ob[r >> 2][r & 3] * fbR;
                float o1 = accO1[r] * faR + ob[4 + (r >> 2)][r & 3] * fbR;
                int q = qbase + crow + 4 * hi;
                size_t base = ((size_t)(b * SDIM + q)) * EMB + h * HD;
                X[base + ln]      = (short)cvt_pk(o0, 0.f);
                X[base + 32 + ln] = (short)cvt_pk(o1, 0.f);
            }
        }
    };

    // ---- single q-tile segment ----
    qbase = qt * QBLK + w * 32;
    q_g = qbase + ln;
    LOAD_Q();
    m2 = -1e30f; l_run = 0.f;
    accO0 = (f32x16){0.f,0.f,0.f,0.f,0.f,0.f,0.f,0.f,0.f,0.f,0.f,0.f,0.f,0.f,0.f,0.f};
    accO1 = accO0;
    const int nt  = 2 * qt + 2;        // always even
    const int cnt = nt >> 1;           // tiles per team
    ISSUE(team * KVB);
    for (int i = 0; i < cnt; ++i) {
        int buf = i & 1;
        WRITE_STAGE(buf);
        int tn = 2 * (i + 1) + team;   // T14: next tile's loads in flight
        if (tn < nt) ISSUE(tn * KVB);
        __builtin_amdgcn_sched_barrier(0);
        __syncthreads();
        int k0 = (2 * i + team) * KVB;
        if (k0 <= qbase + 31) COMPUTE(buf, k0);
    }
    FINISH();
}

// ---------------------------------------------------------------------------
// Output projection: out[i][j] = sum_e X[i][e] * Wo[j][e] + bo[j]
// ---------------------------------------------------------------------------
__global__ __launch_bounds__(256, 2) void proj_gemm(
    const short* __restrict__ X, const float* __restrict__ Wo,
    const float* __restrict__ bo, float* __restrict__ out)
{
    __shared__ short Alds[64][40];
    __shared__ short Blds[64][40];

    int bj = blockIdx.x & 7;
    int bi = blockIdx.x >> 3;
    int i0 = bi * 64, j0 = bj * 64;

    int tid  = threadIdx.x;
    int wave = tid >> 6, lane = tid & 63;
    int g = lane >> 4, ln = lane & 15;
    int srow = tid >> 2, scol = (tid & 3) * 8;

    f32x4 acc[4];
#pragma unroll
    for (int i = 0; i < 4; ++i) acc[i] = (f32x4){0.f, 0.f, 0.f, 0.f};

    for (int e0 = 0; e0 < EMB; e0 += 32) {
        bf16x8 xa = *(const bf16x8*)&X[(size_t)(i0 + srow) * EMB + e0 + scol];
        *(bf16x8*)&Alds[srow][scol] = xa;

        const float* wp = Wo + (size_t)(j0 + srow) * EMB + e0 + scol;
        f32x4 a = *(const f32x4*)wp;
        f32x4 c = *(const f32x4*)(wp + 4);
        u32x4 w = { cvt_pk(a[0], a[1]), cvt_pk(a[2], a[3]),
                    cvt_pk(c[0], c[1]), cvt_pk(c[2], c[3]) };
        *(u32x4*)&Blds[srow][scol] = w;
        __syncthreads();

        bf16x8 af = *(bf16x8*)&Alds[wave * 16 + ln][g * 8];
#pragma unroll
        for (int nt = 0; nt < 4; ++nt) {
            bf16x8 bf = *(bf16x8*)&Blds[nt * 16 + ln][g * 8];
            acc[nt] = __builtin_amdgcn_mfma_f32_16x16x32_bf16(af, bf, acc[nt], 0, 0, 0);
        }
        __syncthreads();
    }

#pragma unroll
    for (int nt = 0; nt < 4; ++nt)
#pragma unroll
        for (int r = 0; r < 4; ++r) {
            int row = i0 + wave * 16 + g * 4 + r;
            int col = j0 + nt * 16 + ln;
            out[(size_t)row * EMB + col] = acc[nt][r] + bo[col];
        }
}

extern "C" void kernel_launch(void* const* d_in, const int* in_sizes, int n_in,
                              void* d_out, int out_size, void* d_ws, size_t ws_size,
                              hipStream_t stream) {
    const float* Q  = (const float*)d_in[0];
    const float* K  = (const float*)d_in[1];
    const float* V  = (const float*)d_in[2];
    const float* Wo = (const float*)d_in[3];
    const float* bo = (const float*)d_in[4];
    short* X   = (short*)d_ws;                 // bf16 attn output [B*S][EMB] = 8 MB
    float* out = (float*)d_out;

    attn_fwd<<<dim3(2 * NB * NH * NPAIR), 512, 0, stream>>>(Q, K, V, X);
    proj_gemm<<<dim3((NB * SDIM / 64) * (EMB / 64)), 256, 0, stream>>>(X, Wo, bo, out);
}

// Round 11
// 129.693 us; speedup vs baseline: 1.8569x; 1.8569x over previous
//
#include <hip/hip_runtime.h>
#include <hip/hip_bf16.h>
#include <math.h>

#define SDIM 4096
#define EMB 512
#define NH 8
#define HD 64
#define QBLK 128            // q-rows per block (4 waves x 32)
#define KVB 64
#define NB 2
#define NQT (SDIM / QBLK)   // 32
#define NPAIR (NQT / 2)     // 16

typedef __attribute__((ext_vector_type(4)))  float f32x4;
typedef __attribute__((ext_vector_type(16))) float f32x16;
typedef __attribute__((ext_vector_type(8)))  short bf16x8;
typedef __attribute__((ext_vector_type(4)))  unsigned u32x4;

#define SCQ 0.18033688011112042f   // log2(e) / sqrt(64), folded into Q
#define THR 8.0f                   // defer-max threshold, log2 units

__device__ __forceinline__ unsigned cvt_pk(float lo, float hi) {
    unsigned r;
    asm("v_cvt_pk_bf16_f32 %0, %1, %2" : "=v"(r) : "v"(lo), "v"(hi));
    return r;
}
__device__ __forceinline__ void pl32swap(unsigned &a, unsigned &b) {
    asm("v_permlane32_swap_b32 %0, %1" : "+v"(a), "+v"(b));
}

// ---------------------------------------------------------------------------
// Flash attention (causal). 512 blocks x 512 threads, 2 blocks/CU co-resident
// (LDS 65KB x2 = 130 <= 160KB) -> 4 waves/SIMD.
// LAUNCH_BOUNDS SEMANTICS (R4-R10 measured): 2nd arg acts as CUDA
// min-BLOCKS/CU on this toolchain: (512,4) -> 32 waves/CU -> 64 regs ->
// spill (R10); (1024,4) -> 64 regs (R5). Default for 512-thr blocks targets
// ~5 waves/EU -> 96-108 regs, no spill (R4/R7). (512,2) -> 16 waves/CU ->
// 128-reg cap >= ~96 demand: no spill under EITHER semantics.
// PLACEMENT (R7 evidence): CU fill is consecutive -> interleave pairs:
// block 2k = heavy q-tile (31-p), 2k+1 = light (p), same bh -> each CU gets
// ~33 team-iters + shared KV stream in L2; 512>256 blocks also enables
// dynamic rebalancing as CUs free up.
// Per block: 2 teams x 4 waves split KV tiles even/odd, private (m,l,O) +
// private double-buffered LDS; 2-way flash-combine. 32x32x16 MFMA, swapped
// QK^T (q lane-local), T12 repack, T13 defer-max, T14 async-STAGE, T2
// XOR-swizzle, T5 setprio.
// ---------------------------------------------------------------------------
__global__ __launch_bounds__(512, 2) void attn_fwd(
    const float* __restrict__ Q, const float* __restrict__ K,
    const float* __restrict__ V, short* __restrict__ X)
{
    __shared__ __align__(16) short smem[32768];   // 64KB: [team][buf][K|V]
    __shared__ float mlb[4][32][2];               // merge: per wave m,l

    int idx  = blockIdx.x;
    int k_   = idx >> 1;                // pair index 0..255
    int s_   = idx & 1;                 // 0 = heavy, 1 = light
    int bh   = k_ & 15;                 // pair shares bh -> shared KV in L2
    int p    = k_ >> 4;
    int qt   = s_ ? p : (NQT - 1 - p);
    int b = bh / NH, h = bh % NH;

    int tid  = threadIdx.x;
    int wave = tid >> 6, lane = tid & 63;
    int team = wave >> 2, w = wave & 3;
    int ln = lane & 31, hi = lane >> 5;
    int swz = 8 * (ln & 7);
    int shbase = 36 * hi;               // (lane&32) + 4*hi

    // per-team staging maps (256 threads per team)
    int ttid = tid & 255;
    const int kr = ttid >> 2, kc = (ttid & 3) * 16;   // K: row kr, 16 d
    const int vp = ttid & 31, vdb = (ttid >> 5) * 8;  // V: kv pair 2vp, 8 d

    // prefetch registers (T14)
    f32x4 pk0, pk1, pk2, pk3, pv0, pv1, pv2, pv3;

    auto ISSUE = [&](int k0) {
        const float* kp = K + ((size_t)(b * SDIM + k0 + kr)) * EMB + h * HD + kc;
        pk0 = *(const f32x4*)(kp + 0);
        pk1 = *(const f32x4*)(kp + 4);
        pk2 = *(const f32x4*)(kp + 8);
        pk3 = *(const f32x4*)(kp + 12);
        const float* v0p = V + ((size_t)(b * SDIM + k0 + 2 * vp)) * EMB + h * HD + vdb;
        pv0 = *(const f32x4*)(v0p);
        pv1 = *(const f32x4*)(v0p + 4);
        pv2 = *(const f32x4*)(v0p + EMB);
        pv3 = *(const f32x4*)(v0p + EMB + 4);
    };

    auto WRITE_STAGE = [&](int buf) {
        short* Klp = &smem[(team * 2 + buf) * 8192];
        short* Vtp = Klp + 4096;
        int rs = 8 * (kr & 7);
        u32x4 w0 = { cvt_pk(pk0[0],pk0[1]), cvt_pk(pk0[2],pk0[3]),
                     cvt_pk(pk1[0],pk1[1]), cvt_pk(pk1[2],pk1[3]) };
        u32x4 w1 = { cvt_pk(pk2[0],pk2[1]), cvt_pk(pk2[2],pk2[3]),
                     cvt_pk(pk3[0],pk3[1]), cvt_pk(pk3[2],pk3[3]) };
        *(u32x4*)&Klp[kr * HD + ((kc + 0) ^ rs)] = w0;
        *(u32x4*)&Klp[kr * HD + ((kc + 8) ^ rs)] = w1;
        unsigned* vt32 = (unsigned*)Vtp;
#pragma unroll
        for (int i = 0; i < 4; ++i) {
            int d = vdb + i;
            vt32[d * 32 + (vp ^ (4 * (d & 7)))] = cvt_pk(pv0[i], pv2[i]);
        }
#pragma unroll
        for (int i = 0; i < 4; ++i) {
            int d = vdb + 4 + i;
            vt32[d * 32 + (vp ^ (4 * (d & 7)))] = cvt_pk(pv1[i], pv3[i]);
        }
    };

    // per-segment state
    bf16x8 qf0, qf1, qf2, qf3;
    float m2, l_run;
    f32x16 accO0, accO1;
    int qbase, q_g;

    auto LOAD_Q = [&]() {   // pre-scaled by SCQ (log2-domain scores from MFMA)
        const float* qp = Q + ((size_t)(b * SDIM + q_g)) * EMB + h * HD + 8 * hi;
#pragma unroll
        for (int s = 0; s < 4; ++s) {
            f32x4 a = *(const f32x4*)(qp + 16 * s) * SCQ;
            f32x4 c = *(const f32x4*)(qp + 16 * s + 4) * SCQ;
            u32x4 wq = { cvt_pk(a[0], a[1]), cvt_pk(a[2], a[3]),
                         cvt_pk(c[0], c[1]), cvt_pk(c[2], c[3]) };
            bf16x8 f = (bf16x8)wq;
            if (s == 0) qf0 = f; else if (s == 1) qf1 = f;
            else if (s == 2) qf2 = f; else qf3 = f;
        }
    };

    auto COMPUTE = [&](int buf, int k0) {
        short* Klp = &smem[(team * 2 + buf) * 8192];
        short* Vtp = Klp + 4096;
        float p0[16], p1[16];
#pragma unroll
        for (int t = 0; t < 2; ++t) {
            f32x16 acc = (f32x16){0.f,0.f,0.f,0.f,0.f,0.f,0.f,0.f,
                                  0.f,0.f,0.f,0.f,0.f,0.f,0.f,0.f};
            __builtin_amdgcn_s_setprio(1);
#pragma unroll
            for (int s = 0; s < 4; ++s) {
                bf16x8 kf = *(bf16x8*)&Klp[(32*t + ln) * HD + ((16*s + 8*hi) ^ swz)];
                bf16x8 qs = (s == 0) ? qf0 : (s == 1) ? qf1 : (s == 2) ? qf2 : qf3;
                acc = __builtin_amdgcn_mfma_f32_32x32x16_bf16(kf, qs, acc, 0, 0, 0);
            }
            __builtin_amdgcn_s_setprio(0);
            float* pt = t ? p1 : p0;
            if (k0 + 32*t + 31 > qbase) {          // diagonal-crossing: mask
#pragma unroll
                for (int r = 0; r < 16; ++r) {
                    int kv = k0 + 32*t + (r & 3) + 8*(r >> 2) + 4*hi;
                    pt[r] = (kv > q_g) ? -INFINITY : acc[r];
                }
            } else {
#pragma unroll
                for (int r = 0; r < 16; ++r) pt[r] = acc[r];
            }
        }

        // tree max
        float mx[16];
#pragma unroll
        for (int r = 0; r < 16; ++r) mx[r] = fmaxf(p0[r], p1[r]);
#pragma unroll
        for (int r = 0; r < 8; ++r) mx[r] = fmaxf(mx[r], mx[r + 8]);
#pragma unroll
        for (int r = 0; r < 4; ++r) mx[r] = fmaxf(mx[r], mx[r + 4]);
        float mt = fmaxf(fmaxf(mx[0], mx[1]), fmaxf(mx[2], mx[3]));
        mt = fmaxf(mt, __shfl_xor(mt, 32, 64));

        if (!__all(mt <= m2 + THR)) {              // T13 defer-max
            float m_new = fmaxf(m2, mt);
            float fac = __builtin_amdgcn_exp2f(m2 - m_new);
            m2 = m_new;
            l_run *= fac;
#pragma unroll
            for (int r = 0; r < 16; ++r) {
                float fr = __shfl(fac, shbase + ((r & 3) + 8*(r >> 2)), 64);
                accO0[r] *= fr;
                accO1[r] *= fr;
            }
        }
        // exp2 + tree sum
        float sm[16];
#pragma unroll
        for (int r = 0; r < 16; ++r) {
            p0[r] = __builtin_amdgcn_exp2f(p0[r] - m2);
            p1[r] = __builtin_amdgcn_exp2f(p1[r] - m2);
            sm[r] = p0[r] + p1[r];
        }
#pragma unroll
        for (int r = 0; r < 8; ++r) sm[r] += sm[r + 8];
#pragma unroll
        for (int r = 0; r < 4; ++r) sm[r] += sm[r + 4];
        float psum = (sm[0] + sm[1]) + (sm[2] + sm[3]);
        psum += __shfl_xor(psum, 32, 64);
        l_run += psum;

        // T12 repack P -> A-frags + PV
#pragma unroll
        for (int s = 0; s < 4; ++s) {
            const float* pt = (s >= 2) ? p1 : p0;
            const int u8 = (s & 1) * 8;
            unsigned w0 = cvt_pk(pt[u8 + 0], pt[u8 + 1]);
            unsigned w2 = cvt_pk(pt[u8 + 4], pt[u8 + 5]);
            pl32swap(w0, w2);
            unsigned w1 = cvt_pk(pt[u8 + 2], pt[u8 + 3]);
            unsigned w3 = cvt_pk(pt[u8 + 6], pt[u8 + 7]);
            pl32swap(w1, w3);
            u32x4 pw = { w0, w1, w2, w3 };
            bf16x8 pa = (bf16x8)pw;
            bf16x8 v0f = *(bf16x8*)&Vtp[(ln)      * KVB + ((16*s + 8*hi) ^ swz)];
            bf16x8 v1f = *(bf16x8*)&Vtp[(32 + ln) * KVB + ((16*s + 8*hi) ^ swz)];
            __builtin_amdgcn_s_setprio(1);
            accO0 = __builtin_amdgcn_mfma_f32_32x32x16_bf16(pa, v0f, accO0, 0, 0, 0);
            accO1 = __builtin_amdgcn_mfma_f32_32x32x16_bf16(pa, v1f, accO1, 0, 0, 0);
            __builtin_amdgcn_s_setprio(0);
        }
    };

    // flash-combine merge (team1 -> LDS, team0 merges + writes X)
    auto FINISH = [&]() {
        __syncthreads();
        f32x4* O4 = (f32x4*)&smem[16384];   // 32KB overlay on team1 KV region
        if (team == 1) {
            if (hi == 0) { mlb[w][ln][0] = m2; mlb[w][ln][1] = l_run; }
#pragma unroll
            for (int rq = 0; rq < 4; ++rq)
                O4[(w * 8 + rq) * 64 + lane] =
                    (f32x4){accO0[4*rq], accO0[4*rq+1], accO0[4*rq+2], accO0[4*rq+3]};
#pragma unroll
            for (int rq = 0; rq < 4; ++rq)
                O4[(w * 8 + 4 + rq) * 64 + lane] =
                    (f32x4){accO1[4*rq], accO1[4*rq+1], accO1[4*rq+2], accO1[4*rq+3]};
        }
        __syncthreads();
        if (team == 0) {
            float mB = mlb[w][ln][0], lB = mlb[w][ln][1];
            float m  = fmaxf(m2, mB);
            float aS = __builtin_amdgcn_exp2f(m2 - m);
            float bS = __builtin_amdgcn_exp2f(mB - m);
            float il = 1.f / (l_run * aS + lB * bS);
            float fa = aS * il, fb = bS * il;
            f32x4 ob[8];
#pragma unroll
            for (int rq = 0; rq < 8; ++rq) ob[rq] = O4[(w * 8 + rq) * 64 + lane];
#pragma unroll
            for (int r = 0; r < 16; ++r) {
                int crow = (r & 3) + 8 * (r >> 2);
                float faR = __shfl(fa, shbase + crow, 64);
                float fbR = __shfl(fb, shbase + crow, 64);
                float o0 = accO0[r] * faR + ob[r >> 2][r & 3] * fbR;
                float o1 = accO1[r] * faR + ob[4 + (r >> 2)][r & 3] * fbR;
                int q = qbase + crow + 4 * hi;
                size_t base = ((size_t)(b * SDIM + q)) * EMB + h * HD;
                X[base + ln]      = (short)cvt_pk(o0, 0.f);
                X[base + 32 + ln] = (short)cvt_pk(o1, 0.f);
            }
        }
    };

    // ---- single q-tile segment ----
    qbase = qt * QBLK + w * 32;
    q_g = qbase + ln;
    LOAD_Q();
    m2 = -1e30f; l_run = 0.f;
    accO0 = (f32x16){0.f,0.f,0.f,0.f,0.f,0.f,0.f,0.f,0.f,0.f,0.f,0.f,0.f,0.f,0.f,0.f};
    accO1 = accO0;
    const int nt  = 2 * qt + 2;        // always even
    const int cnt = nt >> 1;           // tiles per team
    ISSUE(team * KVB);
    for (int i = 0; i < cnt; ++i) {
        int buf = i & 1;
        WRITE_STAGE(buf);
        int tn = 2 * (i + 1) + team;   // T14: next tile's loads in flight
        if (tn < nt) ISSUE(tn * KVB);
        __builtin_amdgcn_sched_barrier(0);
        __syncthreads();
        int k0 = (2 * i + team) * KVB;
        if (k0 <= qbase + 31) COMPUTE(buf, k0);
    }
    FINISH();
}

// ---------------------------------------------------------------------------
// Output projection: out[i][j] = sum_e X[i][e] * Wo[j][e] + bo[j]
// ---------------------------------------------------------------------------
__global__ __launch_bounds__(256, 2) void proj_gemm(
    const short* __restrict__ X, const float* __restrict__ Wo,
    const float* __restrict__ bo, float* __restrict__ out)
{
    __shared__ short Alds[64][40];
    __shared__ short Blds[64][40];

    int bj = blockIdx.x & 7;
    int bi = blockIdx.x >> 3;
    int i0 = bi * 64, j0 = bj * 64;

    int tid  = threadIdx.x;
    int wave = tid >> 6, lane = tid & 63;
    int g = lane >> 4, ln = lane & 15;
    int srow = tid >> 2, scol = (tid & 3) * 8;

    f32x4 acc[4];
#pragma unroll
    for (int i = 0; i < 4; ++i) acc[i] = (f32x4){0.f, 0.f, 0.f, 0.f};

    for (int e0 = 0; e0 < EMB; e0 += 32) {
        bf16x8 xa = *(const bf16x8*)&X[(size_t)(i0 + srow) * EMB + e0 + scol];
        *(bf16x8*)&Alds[srow][scol] = xa;

        const float* wp = Wo + (size_t)(j0 + srow) * EMB + e0 + scol;
        f32x4 a = *(const f32x4*)wp;
        f32x4 c = *(const f32x4*)(wp + 4);
        u32x4 w = { cvt_pk(a[0], a[1]), cvt_pk(a[2], a[3]),
                    cvt_pk(c[0], c[1]), cvt_pk(c[2], c[3]) };
        *(u32x4*)&Blds[srow][scol] = w;
        __syncthreads();

        bf16x8 af = *(bf16x8*)&Alds[wave * 16 + ln][g * 8];
#pragma unroll
        for (int nt = 0; nt < 4; ++nt) {
            bf16x8 bf = *(bf16x8*)&Blds[nt * 16 + ln][g * 8];
            acc[nt] = __builtin_amdgcn_mfma_f32_16x16x32_bf16(af, bf, acc[nt], 0, 0, 0);
        }
        __syncthreads();
    }

#pragma unroll
    for (int nt = 0; nt < 4; ++nt)
#pragma unroll
        for (int r = 0; r < 4; ++r) {
            int row = i0 + wave * 16 + g * 4 + r;
            int col = j0 + nt * 16 + ln;
            out[(size_t)row * EMB + col] = acc[nt][r] + bo[col];
        }
}

extern "C" void kernel_launch(void* const* d_in, const int* in_sizes, int n_in,
                              void* d_out, int out_size, void* d_ws, size_t ws_size,
                              hipStream_t stream) {
    const float* Q  = (const float*)d_in[0];
    const float* K  = (const float*)d_in[1];
    const float* V  = (const float*)d_in[2];
    const float* Wo = (const float*)d_in[3];
    const float* bo = (const float*)d_in[4];
    short* X   = (short*)d_ws;                 // bf16 attn output [B*S][EMB] = 8 MB
    float* out = (float*)d_out;

    attn_fwd<<<dim3(2 * NB * NH * NPAIR), 512, 0, stream>>>(Q, K, V, X);
    proj_gemm<<<dim3((NB * SDIM / 64) * (EMB / 64)), 256, 0, stream>>>(X, Wo, bo, out);
}

// Round 12
// 110.155 us; speedup vs baseline: 2.1862x; 1.1774x over previous
//
#include <hip/hip_runtime.h>
#include <hip/hip_bf16.h>
#include <math.h>

#define SDIM 4096
#define EMB 512
#define NH 8
#define HD 64
#define QBLK 128            // q-rows per block (4 waves x 32)
#define KVB 64
#define NB 2
#define NQT (SDIM / QBLK)   // 32
#define NPAIR (NQT / 2)     // 16

typedef __attribute__((ext_vector_type(4)))  float f32x4;
typedef __attribute__((ext_vector_type(16))) float f32x16;
typedef __attribute__((ext_vector_type(8)))  short bf16x8;
typedef __attribute__((ext_vector_type(4)))  unsigned u32x4;

#define SCQ 0.18033688011112042f   // log2(e) / sqrt(64), folded into Q
#define THR 8.0f                   // defer-max threshold, log2 units

__device__ __forceinline__ unsigned cvt_pk(float lo, float hi) {
    unsigned r;
    asm("v_cvt_pk_bf16_f32 %0, %1, %2" : "=v"(r) : "v"(lo), "v"(hi));
    return r;
}
__device__ __forceinline__ void pl32swap(unsigned &a, unsigned &b) {
    asm("v_permlane32_swap_b32 %0, %1" : "+v"(a), "+v"(b));
}
// async global->LDS, 16B per lane. LDS arg must be wave-uniform base;
// per-lane dst = base + lane*16. Global arg is the per-lane address.
__device__ __forceinline__ void gl_lds16(const void* g, void* l) {
    __builtin_amdgcn_global_load_lds(
        (const __attribute__((address_space(1))) unsigned*)(unsigned long long)g,
        (__attribute__((address_space(3))) unsigned*)(unsigned)(unsigned long long)l,
        16, 0, 0);
}

// ---------------------------------------------------------------------------
// prep: build bf16 pre-swizzled tile images of K and V in d_ws so the attn
// kernel can stage with linear global_load_lds (m173 pattern: swizzle baked
// into the global image). K image: [bh][kv][64] with row-XOR swizzle.
// V image: per (b,h) 64-row tile, transposed [d][64] with kv-pair packing
// and the same XOR swizzle (exact byte image of the old WRITE_STAGE LDS).
// ---------------------------------------------------------------------------
__global__ __launch_bounds__(256) void prep(
    const float* __restrict__ K, const float* __restrict__ V,
    short* __restrict__ Kb, short* __restrict__ Vt)
{
    __shared__ float vls[64][65];
    int isV  = blockIdx.x >> 10;
    int id   = blockIdx.x & 1023;
    int bh   = id >> 6, tile = id & 63;
    int b = bh >> 3, h = bh & 7;
    int k0 = tile * 64;
    int t = threadIdx.x;
    int r = t >> 2, c0 = (t & 3) * 16;

    if (!isV) {
        const float* kp = K + ((size_t)(b * SDIM + k0 + r)) * EMB + h * HD + c0;
        f32x4 a0 = *(const f32x4*)(kp + 0);
        f32x4 a1 = *(const f32x4*)(kp + 4);
        f32x4 a2 = *(const f32x4*)(kp + 8);
        f32x4 a3 = *(const f32x4*)(kp + 12);
        int rs = 8 * (r & 7);
        u32x4 w0 = { cvt_pk(a0[0],a0[1]), cvt_pk(a0[2],a0[3]),
                     cvt_pk(a1[0],a1[1]), cvt_pk(a1[2],a1[3]) };
        u32x4 w1 = { cvt_pk(a2[0],a2[1]), cvt_pk(a2[2],a2[3]),
                     cvt_pk(a3[0],a3[1]), cvt_pk(a3[2],a3[3]) };
        short* dst = Kb + ((size_t)(bh * SDIM + k0 + r)) * 64;
        *(u32x4*)&dst[(c0 + 0) ^ rs] = w0;
        *(u32x4*)&dst[(c0 + 8) ^ rs] = w1;
    } else {
        const float* vp = V + ((size_t)(b * SDIM + k0 + r)) * EMB + h * HD + c0;
        *(f32x4*)&vls[r][c0 + 0]  = *(const f32x4*)(vp + 0);
        *(f32x4*)&vls[r][c0 + 4]  = *(const f32x4*)(vp + 4);
        *(f32x4*)&vls[r][c0 + 8]  = *(const f32x4*)(vp + 8);
        *(f32x4*)&vls[r][c0 + 12] = *(const f32x4*)(vp + 12);
        __syncthreads();
        int d = r, x0 = c0;
        int ss = 4 * (d & 7);
        unsigned wv[8];
#pragma unroll
        for (int i = 0; i < 8; ++i) {
            int vpx = ((x0 >> 1) + i) ^ ss;
            wv[i] = cvt_pk(vls[2 * vpx][d], vls[2 * vpx + 1][d]);
        }
        short* dst = Vt + ((size_t)bh * 64 + tile) * 4096 + d * 64 + x0;
        *(u32x4*)&dst[0] = (u32x4){ wv[0], wv[1], wv[2], wv[3] };
        *(u32x4*)&dst[8] = (u32x4){ wv[4], wv[5], wv[6], wv[7] };
    }
}

// ---------------------------------------------------------------------------
// Flash attention (causal). 512 blocks x 512 threads, LDS exactly 64KB
// (mlb overlaid into dead staging at FINISH) -> 2 blocks/CU co-residency
// target (R11 lesson: 65KB x2 = 133KB did NOT co-reside; usable ~128KB).
// Interleaved pairing: block 2k = heavy qt (31-p), 2k+1 = light (p), same
// bh -> balanced CU composition under consecutive fill (R7 evidence).
// Staging: global_load_lds from prep's pre-swizzled bf16 images — 4 instrs
// per thread/iter, no conversion VALU, no prefetch registers. Schedule:
// {barrier; issue(next -> buf^1); compute(buf)} — DMA flies under compute,
// barrier auto-drain is free, buffer WAR race barrier-separated.
// 2 teams x 4 waves split KV tiles even/odd; 2-way flash-combine in LDS.
// ---------------------------------------------------------------------------
__global__ __launch_bounds__(512, 2) void attn_fwd(
    const float* __restrict__ Q, const short* __restrict__ Kb,
    const short* __restrict__ Vt, short* __restrict__ X)
{
    __shared__ __align__(16) short smem[32768];   // exactly 64KB

    int idx  = blockIdx.x;
    int k_   = idx >> 1;                // pair index
    int s_   = idx & 1;                 // 0 = heavy, 1 = light
    int bh   = k_ & 15;
    int p    = k_ >> 4;
    int qt   = s_ ? p : (NQT - 1 - p);
    int b = bh >> 3, h = bh & 7;

    int tid  = threadIdx.x;
    int wave = tid >> 6, lane = tid & 63;
    int team = wave >> 2, w = wave & 3;
    int ln = lane & 31, hi = lane >> 5;
    int swz = 8 * (ln & 7);
    int shbase = 36 * hi;               // (lane&32) + 4*hi

    const short* KbT = Kb + (size_t)bh * SDIM * 64;
    const short* VtT = Vt + (size_t)bh * 64 * 4096;

    // stage one 64-kv tile (K 8KB + V 8KB) for this team via global_load_lds
    auto ISSUE = [&](int buf, int tile) {
        short* Kl = &smem[(team * 2 + buf) * 8192];
        const short* gK = KbT + (size_t)tile * 64 * 64;
        const short* gV = VtT + (size_t)tile * 4096;
        int off = w * 1024 + lane * 8;
        gl_lds16(gK + off,       Kl + w * 1024);
        gl_lds16(gK + off + 512, Kl + w * 1024 + 512);
        gl_lds16(gV + off,       Kl + 4096 + w * 1024);
        gl_lds16(gV + off + 512, Kl + 4096 + w * 1024 + 512);
    };

    // per-segment state
    bf16x8 qf0, qf1, qf2, qf3;
    float m2, l_run;
    f32x16 accO0, accO1;
    int qbase, q_g;

    auto LOAD_Q = [&]() {   // pre-scaled by SCQ (log2-domain scores from MFMA)
        const float* qp = Q + ((size_t)(b * SDIM + q_g)) * EMB + h * HD + 8 * hi;
#pragma unroll
        for (int s = 0; s < 4; ++s) {
            f32x4 a = *(const f32x4*)(qp + 16 * s) * SCQ;
            f32x4 c = *(const f32x4*)(qp + 16 * s + 4) * SCQ;
            u32x4 wq = { cvt_pk(a[0], a[1]), cvt_pk(a[2], a[3]),
                         cvt_pk(c[0], c[1]), cvt_pk(c[2], c[3]) };
            bf16x8 f = (bf16x8)wq;
            if (s == 0) qf0 = f; else if (s == 1) qf1 = f;
            else if (s == 2) qf2 = f; else qf3 = f;
        }
    };

    auto COMPUTE = [&](int buf, int k0) {
        short* Klp = &smem[(team * 2 + buf) * 8192];
        short* Vtp = Klp + 4096;
        float p0[16], p1[16];
#pragma unroll
        for (int t = 0; t < 2; ++t) {
            f32x16 acc = (f32x16){0.f,0.f,0.f,0.f,0.f,0.f,0.f,0.f,
                                  0.f,0.f,0.f,0.f,0.f,0.f,0.f,0.f};
            __builtin_amdgcn_s_setprio(1);
#pragma unroll
            for (int s = 0; s < 4; ++s) {
                bf16x8 kf = *(bf16x8*)&Klp[(32*t + ln) * HD + ((16*s + 8*hi) ^ swz)];
                bf16x8 qs = (s == 0) ? qf0 : (s == 1) ? qf1 : (s == 2) ? qf2 : qf3;
                acc = __builtin_amdgcn_mfma_f32_32x32x16_bf16(kf, qs, acc, 0, 0, 0);
            }
            __builtin_amdgcn_s_setprio(0);
            float* pt = t ? p1 : p0;
            if (k0 + 32*t + 31 > qbase) {          // diagonal-crossing: mask
#pragma unroll
                for (int r = 0; r < 16; ++r) {
                    int kv = k0 + 32*t + (r & 3) + 8*(r >> 2) + 4*hi;
                    pt[r] = (kv > q_g) ? -INFINITY : acc[r];
                }
            } else {
#pragma unroll
                for (int r = 0; r < 16; ++r) pt[r] = acc[r];
            }
        }

        // tree max
        float mx[16];
#pragma unroll
        for (int r = 0; r < 16; ++r) mx[r] = fmaxf(p0[r], p1[r]);
#pragma unroll
        for (int r = 0; r < 8; ++r) mx[r] = fmaxf(mx[r], mx[r + 8]);
#pragma unroll
        for (int r = 0; r < 4; ++r) mx[r] = fmaxf(mx[r], mx[r + 4]);
        float mt = fmaxf(fmaxf(mx[0], mx[1]), fmaxf(mx[2], mx[3]));
        mt = fmaxf(mt, __shfl_xor(mt, 32, 64));

        if (!__all(mt <= m2 + THR)) {              // T13 defer-max
            float m_new = fmaxf(m2, mt);
            float fac = __builtin_amdgcn_exp2f(m2 - m_new);
            m2 = m_new;
            l_run *= fac;
#pragma unroll
            for (int r = 0; r < 16; ++r) {
                float fr = __shfl(fac, shbase + ((r & 3) + 8*(r >> 2)), 64);
                accO0[r] *= fr;
                accO1[r] *= fr;
            }
        }
        // exp2 + tree sum
        float sm[16];
#pragma unroll
        for (int r = 0; r < 16; ++r) {
            p0[r] = __builtin_amdgcn_exp2f(p0[r] - m2);
            p1[r] = __builtin_amdgcn_exp2f(p1[r] - m2);
            sm[r] = p0[r] + p1[r];
        }
#pragma unroll
        for (int r = 0; r < 8; ++r) sm[r] += sm[r + 8];
#pragma unroll
        for (int r = 0; r < 4; ++r) sm[r] += sm[r + 4];
        float psum = (sm[0] + sm[1]) + (sm[2] + sm[3]);
        psum += __shfl_xor(psum, 32, 64);
        l_run += psum;

        // T12 repack P -> A-frags + PV
#pragma unroll
        for (int s = 0; s < 4; ++s) {
            const float* pt = (s >= 2) ? p1 : p0;
            const int u8 = (s & 1) * 8;
            unsigned w0 = cvt_pk(pt[u8 + 0], pt[u8 + 1]);
            unsigned w2 = cvt_pk(pt[u8 + 4], pt[u8 + 5]);
            pl32swap(w0, w2);
            unsigned w1 = cvt_pk(pt[u8 + 2], pt[u8 + 3]);
            unsigned w3 = cvt_pk(pt[u8 + 6], pt[u8 + 7]);
            pl32swap(w1, w3);
            u32x4 pw = { w0, w1, w2, w3 };
            bf16x8 pa = (bf16x8)pw;
            bf16x8 v0f = *(bf16x8*)&Vtp[(ln)      * KVB + ((16*s + 8*hi) ^ swz)];
            bf16x8 v1f = *(bf16x8*)&Vtp[(32 + ln) * KVB + ((16*s + 8*hi) ^ swz)];
            __builtin_amdgcn_s_setprio(1);
            accO0 = __builtin_amdgcn_mfma_f32_32x32x16_bf16(pa, v0f, accO0, 0, 0, 0);
            accO1 = __builtin_amdgcn_mfma_f32_32x32x16_bf16(pa, v1f, accO1, 0, 0, 0);
            __builtin_amdgcn_s_setprio(0);
        }
    };

    // flash-combine merge (team1 -> LDS, team0 merges + writes X).
    // mlb overlaid at smem bytes [0,1024) (team0-buf0 K region, dead here);
    // O overlay at bytes [32768,65536) (team1's buffers, dead here).
    auto FINISH = [&]() {
        __syncthreads();
        float* mlF = (float*)smem;
        f32x4* O4  = (f32x4*)&smem[16384];
        if (team == 1) {
            if (hi == 0) { mlF[w * 64 + ln * 2] = m2; mlF[w * 64 + ln * 2 + 1] = l_run; }
#pragma unroll
            for (int rq = 0; rq < 4; ++rq)
                O4[(w * 8 + rq) * 64 + lane] =
                    (f32x4){accO0[4*rq], accO0[4*rq+1], accO0[4*rq+2], accO0[4*rq+3]};
#pragma unroll
            for (int rq = 0; rq < 4; ++rq)
                O4[(w * 8 + 4 + rq) * 64 + lane] =
                    (f32x4){accO1[4*rq], accO1[4*rq+1], accO1[4*rq+2], accO1[4*rq+3]};
        }
        __syncthreads();
        if (team == 0) {
            float mB = mlF[w * 64 + ln * 2], lB = mlF[w * 64 + ln * 2 + 1];
            float m  = fmaxf(m2, mB);
            float aS = __builtin_amdgcn_exp2f(m2 - m);
            float bS = __builtin_amdgcn_exp2f(mB - m);
            float il = 1.f / (l_run * aS + lB * bS);
            float fa = aS * il, fb = bS * il;
            f32x4 ob[8];
#pragma unroll
            for (int rq = 0; rq < 8; ++rq) ob[rq] = O4[(w * 8 + rq) * 64 + lane];
#pragma unroll
            for (int r = 0; r < 16; ++r) {
                int crow = (r & 3) + 8 * (r >> 2);
                float faR = __shfl(fa, shbase + crow, 64);
                float fbR = __shfl(fb, shbase + crow, 64);
                float o0 = accO0[r] * faR + ob[r >> 2][r & 3] * fbR;
                float o1 = accO1[r] * faR + ob[4 + (r >> 2)][r & 3] * fbR;
                int q = qbase + crow + 4 * hi;
                size_t base = ((size_t)(b * SDIM + q)) * EMB + h * HD;
                X[base + ln]      = (short)cvt_pk(o0, 0.f);
                X[base + 32 + ln] = (short)cvt_pk(o1, 0.f);
            }
        }
    };

    // ---- single q-tile segment ----
    qbase = qt * QBLK + w * 32;
    q_g = qbase + ln;
    LOAD_Q();
    m2 = -1e30f; l_run = 0.f;
    accO0 = (f32x16){0.f,0.f,0.f,0.f,0.f,0.f,0.f,0.f,0.f,0.f,0.f,0.f,0.f,0.f,0.f,0.f};
    accO1 = accO0;
    const int nt  = 2 * qt + 2;        // always even
    const int cnt = nt >> 1;           // tiles per team (even/odd split)
    ISSUE(0, team);                    // prologue: team's first tile -> buf0
    int buf = 0;
    for (int i = 0; i < cnt; ++i) {
        __syncthreads();               // tile i staged (own loads drained pre-
                                       // barrier by all waves); prior readers done
        if (i + 1 < cnt) ISSUE(buf ^ 1, 2 * (i + 1) + team);  // flies under compute
        int k0 = (2 * i + team) * KVB;
        if (k0 <= qbase + 31) COMPUTE(buf, k0);
        buf ^= 1;
    }
    FINISH();
}

// ---------------------------------------------------------------------------
// Output projection: out[i][j] = sum_e X[i][e] * Wo[j][e] + bo[j]
// ---------------------------------------------------------------------------
__global__ __launch_bounds__(256, 2) void proj_gemm(
    const short* __restrict__ X, const float* __restrict__ Wo,
    const float* __restrict__ bo, float* __restrict__ out)
{
    __shared__ short Alds[64][40];
    __shared__ short Blds[64][40];

    int bj = blockIdx.x & 7;
    int bi = blockIdx.x >> 3;
    int i0 = bi * 64, j0 = bj * 64;

    int tid  = threadIdx.x;
    int wave = tid >> 6, lane = tid & 63;
    int g = lane >> 4, ln = lane & 15;
    int srow = tid >> 2, scol = (tid & 3) * 8;

    f32x4 acc[4];
#pragma unroll
    for (int i = 0; i < 4; ++i) acc[i] = (f32x4){0.f, 0.f, 0.f, 0.f};

    for (int e0 = 0; e0 < EMB; e0 += 32) {
        bf16x8 xa = *(const bf16x8*)&X[(size_t)(i0 + srow) * EMB + e0 + scol];
        *(bf16x8*)&Alds[srow][scol] = xa;

        const float* wp = Wo + (size_t)(j0 + srow) * EMB + e0 + scol;
        f32x4 a = *(const f32x4*)wp;
        f32x4 c = *(const f32x4*)(wp + 4);
        u32x4 w = { cvt_pk(a[0], a[1]), cvt_pk(a[2], a[3]),
                    cvt_pk(c[0], c[1]), cvt_pk(c[2], c[3]) };
        *(u32x4*)&Blds[srow][scol] = w;
        __syncthreads();

        bf16x8 af = *(bf16x8*)&Alds[wave * 16 + ln][g * 8];
#pragma unroll
        for (int nt = 0; nt < 4; ++nt) {
            bf16x8 bf = *(bf16x8*)&Blds[nt * 16 + ln][g * 8];
            acc[nt] = __builtin_amdgcn_mfma_f32_16x16x32_bf16(af, bf, acc[nt], 0, 0, 0);
        }
        __syncthreads();
    }

#pragma unroll
    for (int nt = 0; nt < 4; ++nt)
#pragma unroll
        for (int r = 0; r < 4; ++r) {
            int row = i0 + wave * 16 + g * 4 + r;
            int col = j0 + nt * 16 + ln;
            out[(size_t)row * EMB + col] = acc[nt][r] + bo[col];
        }
}

extern "C" void kernel_launch(void* const* d_in, const int* in_sizes, int n_in,
                              void* d_out, int out_size, void* d_ws, size_t ws_size,
                              hipStream_t stream) {
    const float* Q  = (const float*)d_in[0];
    const float* K  = (const float*)d_in[1];
    const float* V  = (const float*)d_in[2];
    const float* Wo = (const float*)d_in[3];
    const float* bo = (const float*)d_in[4];
    short* Kb = (short*)d_ws;                                        // 8 MB
    short* Vt = (short*)((char*)d_ws + (size_t)8 * 1024 * 1024);     // 8 MB
    short* X  = (short*)((char*)d_ws + (size_t)16 * 1024 * 1024);    // 8 MB
    float* out = (float*)d_out;

    prep<<<dim3(2048), 256, 0, stream>>>(K, V, Kb, Vt);
    attn_fwd<<<dim3(2 * NB * NH * NPAIR), 512, 0, stream>>>(Q, Kb, Vt, X);
    proj_gemm<<<dim3((NB * SDIM / 64) * (EMB / 64)), 256, 0, stream>>>(X, Wo, bo, out);
}